// Round 3
// baseline (18.701 us; speedup 1.0000x reference)
//
#include <hip/hip_runtime.h>
#include <math.h>

// Reranker tie-aware RankNet loss — R3.
// B=4096 rows, n=64. One 64-lane wave per row (4096 waves):
//   - group-end index e via ONE __ballot + ctz (no scan shuffles)
//   - mask (y_true[a] > y_true[b]) == (b > e(a));  cnt = 63 - e  (analytic)
//   - pred broadcast via __builtin_amdgcn_readlane (v_readlane, NOT ds_bpermute)
//   - softplus via hardware v_exp_f32 / v_log_f32 (__expf/__logf)
// Two-stage deterministic reduction: per-block partials -> finalize kernel.

#define N 64
#define WPB 4  // waves (rows) per 256-thread block

__device__ __forceinline__ float readlane_f(float v, int srclane) {
    return __int_as_float(__builtin_amdgcn_readlane(__float_as_int(v), srclane));
}

__global__ __launch_bounds__(256) void rank_loss_partial(
    const float* __restrict__ logits, const int* __restrict__ kd,
    float2* __restrict__ partials, int B)
{
    const int lane = threadIdx.x & 63;
    const int wave = threadIdx.x >> 6;
    const int row  = blockIdx.x * WPB + wave;

    float acc0 = 0.f, acc1 = 0.f, acc2 = 0.f, acc3 = 0.f;
    float cnt = 0.f;

    if (row < B) {
        const int base = row * N + lane;
        const int   k    = kd[base];
        const float pred = logits[base];

        // group-end lane e: smallest j >= lane with (j==63 or k[j]!=k[j+1])
        const int knext = __shfl_down(k, 1);             // lane 63 value unused
        unsigned long long endm = __ballot(lane == 63 || k != knext);
        unsigned long long m = endm >> lane;             // bit 0 == this lane
        const int e = lane + (__ffsll((long long)m) - 1);
        cnt = (float)(63 - e);                           // pairs this lane wins

        #pragma unroll
        for (int b = 0; b < N; ++b) {
            float pb = readlane_f(pred, b);              // SGPR broadcast
            float z  = pb - pred;                        // -(pred_a - pred_b)
            float sp = fmaxf(z, 0.f) + __logf(1.f + __expf(-fabsf(z)));
            float add = (b > e) ? sp : 0.f;
            switch (b & 3) {                             // literal after unroll
                case 0: acc0 += add; break;
                case 1: acc1 += add; break;
                case 2: acc2 += add; break;
                default: acc3 += add; break;
            }
        }
    }

    float psum = (acc0 + acc1) + (acc2 + acc3);
    // wave reduction (64 lanes)
    #pragma unroll
    for (int off = 32; off; off >>= 1) {
        psum += __shfl_down(psum, off);
        cnt  += __shfl_down(cnt,  off);
    }
    __shared__ float ssum[WPB], scnt[WPB];
    if (lane == 0) { ssum[wave] = psum; scnt[wave] = cnt; }
    __syncthreads();
    if (threadIdx.x == 0) {
        float s = 0.f, c = 0.f;
        #pragma unroll
        for (int w = 0; w < WPB; ++w) { s += ssum[w]; c += scnt[w]; }
        partials[blockIdx.x] = make_float2(s, c);
    }
}

__global__ __launch_bounds__(256) void rank_loss_final(
    const float2* __restrict__ partials, float* __restrict__ out, int nPartials)
{
    const int t = threadIdx.x;
    float s = 0.f, c = 0.f;
    for (int i = t; i < nPartials; i += 256) {
        float2 p = partials[i];
        s += p.x; c += p.y;
    }
    #pragma unroll
    for (int off = 32; off; off >>= 1) {
        s += __shfl_down(s, off);
        c += __shfl_down(c, off);
    }
    __shared__ float ss[4], sc[4];
    const int lane = t & 63, wavei = t >> 6;
    if (lane == 0) { ss[wavei] = s; sc[wavei] = c; }
    __syncthreads();
    if (t == 0) {
        float S = 0.f, C = 0.f;
        #pragma unroll
        for (int w = 0; w < 4; ++w) { S += ss[w]; C += sc[w]; }
        out[0] = S / C;
    }
}

extern "C" void kernel_launch(void* const* d_in, const int* in_sizes, int n_in,
                              void* d_out, int out_size, void* d_ws, size_t ws_size,
                              hipStream_t stream) {
    const float* logits = (const float*)d_in[0];
    const int*   kd     = (const int*)d_in[1];
    float*       out    = (float*)d_out;
    const int B = in_sizes[1] / N;              // 4096
    const int nBlocks = (B + WPB - 1) / WPB;    // 1024
    float2* partials = (float2*)d_ws;           // 8 KiB of ws

    rank_loss_partial<<<nBlocks, 256, 0, stream>>>(logits, kd, partials, B);
    rank_loss_final<<<1, 256, 0, stream>>>(partials, out, nBlocks);
}